// Round 3
// baseline (243.814 us; speedup 1.0000x reference)
//
#include <hip/hip_runtime.h>
#include <math.h>

#define B_   256
#define S_   512
#define NQ_  1000
#define MEM_ 20
#define DK_  50
#define DV_  200
#define FC_  50
#define RPB  4
#define CHK  16             // readout chunk count (MFMA tile = 32 rows)
#define CLEN (S_/CHK)       // 32 steps per chunk
#define NKS  7              // K-steps for MFMA (K = 224 = 200 reads + 24 zero)
#define XS_STRIDE 232       // LDS row stride in bf16 (224 + 8 pad)
#define CORRF_STRIDE 24     // floats per corr row (20 used + 4 pad -> 96B, 16B-aligned)
#define NB_EA    ((2*NQ_+1+RPB-1)/RPB)   // 501
#define NB_CORR  4
#define NB_WPACK 7
#define NB_HQ    251
#define PREP_BLOCKS (NB_EA+NB_CORR+NB_WPACK+NB_HQ)   // 763

typedef __attribute__((ext_vector_type(8))) short bf16x8_t;
typedef __attribute__((ext_vector_type(4))) float f32x4_t;
typedef __attribute__((ext_vector_type(2))) float f32x2_t;

static __device__ __forceinline__ f32x2_t pkfma32(f32x2_t a, f32x2_t b, f32x2_t c){
  return __builtin_elementwise_fma(a, b, c);     // -> v_pk_fma_f32 (full rate)
}
static __device__ __forceinline__ unsigned short f2bf(float f){
  unsigned u = __float_as_uint(f);
  unsigned r = u + 0x7fffu + ((u >> 16) & 1u);   // round-to-nearest-even
  return (unsigned short)(r >> 16);
}
static __device__ __forceinline__ float ftanh(float x){
  float e = __expf(2.f*x);
  return 1.f - 2.f*__builtin_amdgcn_rcpf(e+1.f);
}
static __device__ __forceinline__ float fsigm(float x){
  return __builtin_amdgcn_rcpf(1.f+__expf(-x));
}

#define RFL(x) __builtin_amdgcn_readfirstlane(x)

struct corr20 { float4 v0, v1, v2, v3, v4; };

// K0: prep — [0,501): eaTabF (f32 (e,a) pairs); [501,505): corrF (f32);
// [505,512): WpFrag+pwPad; [512,763): hq.  All independent sub-jobs, one grid
// (r15 lesson: serialized small-grid dispatches idle the machine).
__global__ __launch_bounds__(256) void k_prep1(
    const float* __restrict__ qaw,
    const float* __restrict__ ew, const float* __restrict__ eb,
    const float* __restrict__ aw, const float* __restrict__ ab,
    float2* __restrict__ eaTabF,
    const float* __restrict__ qw, const float* __restrict__ mk,
    float* __restrict__ corrF,
    const float* __restrict__ rw, const float* __restrict__ rb,
    const float* __restrict__ pw,
    unsigned short* __restrict__ WpFrag, float* __restrict__ pwPad,
    float* __restrict__ hq){
  __shared__ float qa[RPB*DV_];
  int blk = blockIdx.x;
  if(blk < NB_EA){
    int row0 = blk*RPB;
    for(int i=threadIdx.x; i<RPB*DV_; i+=256){
      int r = i/DV_, cc = i - r*DV_;
      int row = row0 + r;
      qa[i] = (row <= 2*NQ_) ? qaw[row*DV_+cc] : 0.f;
    }
    __syncthreads();
    int d = threadIdx.x;
    if(d >= DV_) return;
    float accE[RPB], accA[RPB];
    #pragma unroll
    for(int r=0;r<RPB;++r){ accE[r] = eb[d]; accA[r] = ab[d]; }
    float we0 = ew[d], wa0 = aw[d];
    for(int j=0;j<DV_;++j){
      int jn = (j+1 < DV_) ? j+1 : j;
      float we1 = ew[jn*DV_+d];
      float wa1 = aw[jn*DV_+d];
      #pragma unroll
      for(int r=0;r<RPB;++r){
        float x = qa[r*DV_+j];
        accE[r] = fmaf(x, we0, accE[r]);
        accA[r] = fmaf(x, wa0, accA[r]);
      }
      we0 = we1; wa0 = wa1;
    }
    #pragma unroll
    for(int r=0;r<RPB;++r){
      int row = row0 + r;
      if(row <= 2*NQ_)
        eaTabF[(size_t)row*DV_+d] = make_float2(fsigm(accE[r]), ftanh(accA[r]));
    }
  } else if(blk < NB_EA+NB_CORR){
    int q = (blk-NB_EA)*256 + threadIdx.x;
    if(q > NQ_) return;
    float qv[DK_];
    #pragma unroll
    for(int j=0;j<DK_;++j) qv[j] = qw[q*DK_+j];
    float s[MEM_]; float mx = -1e30f;
    #pragma unroll
    for(int m=0;m<MEM_;++m){
      float acc = 0.f;
      #pragma unroll
      for(int j=0;j<DK_;++j) acc = fmaf(qv[j], mk[m*DK_+j], acc);
      s[m] = acc; mx = fmaxf(mx, acc);
    }
    float sum = 0.f;
    #pragma unroll
    for(int m=0;m<MEM_;++m){ s[m] = __expf(s[m]-mx); sum += s[m]; }
    float inv = __builtin_amdgcn_rcpf(sum);
    #pragma unroll
    for(int m=0;m<MEM_;++m) corrF[q*CORRF_STRIDE+m] = s[m]*inv;
  } else if(blk < NB_EA+NB_CORR+NB_WPACK){
    int ks = blk - (NB_EA+NB_CORR);
    int nt = threadIdx.x >> 6;
    int lane = threadIdx.x & 63;
    int quad = lane >> 4, col = lane & 15;
    int n = nt*16 + col;
    unsigned short tmp[8];
    #pragma unroll
    for(int j=0;j<8;++j){
      int k = ks*32 + quad*8 + j;
      tmp[j] = (k < DV_ && n < FC_) ? f2bf(rw[k*FC_+n]) : (unsigned short)0;
    }
    uint4* dst = reinterpret_cast<uint4*>(WpFrag + ((size_t)(ks*4+nt)*64 + lane)*8);
    *dst = *reinterpret_cast<const uint4*>(tmp);
    if(ks == 0 && threadIdx.x < 64)
      pwPad[threadIdx.x] = (threadIdx.x < FC_) ? pw[threadIdx.x] : 0.f;
  } else {
    int idx = (blk-(NB_EA+NB_CORR+NB_WPACK))*256 + threadIdx.x;
    int q = idx >> 6, n = idx & 63;
    if(q > NQ_) return;
    float v = 0.f;
    if(n < FC_){
      float acc = rb[n];
      #pragma unroll
      for(int j=0;j<DK_;++j)
        acc = fmaf(qw[q*DK_+j], rw[(DV_+j)*FC_+n], acc);
      v = acc;
    }
    hq[q*64+n] = v;
  }
}

// K1: k_seq — one block per sequence b, sequential 512-step scan in fp32
// (v_pk_fma_f32 pairs; same instr count as f16 version, no drift), MFMA
// readout fused every 32 steps.  Eliminates k_scanA + k_prefix + ABu/Mv0p
// (the ~2x redundant scan work that dominated rounds 0-2).
// 1 block/CU -> all latency exposed: ea gather depth 4 (idx regs depth 8),
// corr per-lane VMEM depth 4 (uniform addr -> single L2 line broadcast),
// qpre/hq rolled one chunk ahead.
__global__ __launch_bounds__(256,1) void k_seq(const int* __restrict__ qd,
    const int* __restrict__ qad,
    const float* __restrict__ corrF,
    const float2* __restrict__ eaTabF,
    const float* __restrict__ mv0,
    const unsigned short* __restrict__ WpFrag,
    const float* __restrict__ hq,
    const float* __restrict__ pwPad, const float* __restrict__ pb,
    const float* __restrict__ target,
    float* __restrict__ out, float2* __restrict__ partials){
  __shared__ unsigned short Xs[CLEN*XS_STRIDE];   // 14,848 B
  __shared__ float sred[2][2][16];
  __shared__ float sbce[4];

  const int b = blockIdx.x;
  const int d = threadIdx.x;
  const int dc = (d < DV_) ? d : DV_-1;
  const bool act = (d < DV_);
  const bool padw = (d < 224);
  const int* __restrict__ qp  = qd  + b*S_;
  const int* __restrict__ qap = qad + b*S_;

  const int wave = threadIdx.x >> 6;
  const int lane = threadIdx.x & 63;
  const int col  = lane & 15, quad = lane >> 4;
  const int rt   = wave & 1;
  const int nh   = wave >> 1;
  const int mbase = rt*16;

  // ---- fp32 scan state: 10 (even,odd) m-pairs per d ----
  f32x2_t Mv[MEM_/2];
  #pragma unroll
  for(int i=0;i<MEM_/2;++i)
    Mv[i] = (f32x2_t){ mv0[(2*i)*DV_+dc], mv0[(2*i+1)*DV_+dc] };

  #define LD_EAF(DST, ROW) { int _r = RFL(ROW); DST = eaTabF[(size_t)_r*DV_ + dc]; }
  #define LD_CORRF(CS, QV) { const float4* _p = (const float4*)(corrF + (size_t)(QV)*CORRF_STRIDE); \
    CS.v0=_p[0]; CS.v1=_p[1]; CS.v2=_p[2]; CS.v3=_p[3]; CS.v4=_p[4]; }

  // ---- prime: ea/corr for steps 0..3, index regs for steps 4..7 ----
  float2 ea0, ea1, ea2, ea3;
  LD_EAF(ea0, qap[0])  LD_EAF(ea1, qap[1])  LD_EAF(ea2, qap[2])  LD_EAF(ea3, qap[3])
  corr20 cs0, cs1, cs2, cs3;
  { int t0=qp[0], t1=qp[1], t2=qp[2], t3=qp[3];
    LD_CORRF(cs0, t0) LD_CORRF(cs1, t1) LD_CORRF(cs2, t2) LD_CORRF(cs3, t3) }
  int qa_i0=qap[4], qa_i1=qap[5], qa_i2=qap[6], qa_i3=qap[7];
  int qv_i0=qp[4],  qv_i1=qp[5],  qv_i2=qp[6],  qv_i3=qp[7];

  int qpreC[4];
  #pragma unroll
  for(int reg=0;reg<4;++reg) qpreC[reg] = qp[mbase + quad*4 + reg];
  float pwv[2];
  #pragma unroll
  for(int j=0;j<2;++j) pwv[j] = pwPad[(nh*2+j)*16 + col];
  const float pbv = pb[0];

  float bceAcc = 0.f, cntAcc = 0.f;

  #define PAIR(CPX, CPY, i) { \
    f32x2_t cp = {CPX, CPY}; \
    racc = pkfma32(cp, Mv[i], racc); \
    f32x2_t tt_ = pkfma32(-Mv[i], ee, aa); \
    Mv[i] = pkfma32(cp, tt_, Mv[i]); }
  #define STEP(TT_, EA, CS) { \
    f32x2_t ee = {EA.x, EA.x}, aa = {EA.y, EA.y}; \
    f32x2_t racc = {0.f, 0.f}; \
    PAIR(CS.v0.x, CS.v0.y, 0) PAIR(CS.v0.z, CS.v0.w, 1) \
    PAIR(CS.v1.x, CS.v1.y, 2) PAIR(CS.v1.z, CS.v1.w, 3) \
    PAIR(CS.v2.x, CS.v2.y, 4) PAIR(CS.v2.z, CS.v2.w, 5) \
    PAIR(CS.v3.x, CS.v3.y, 6) PAIR(CS.v3.z, CS.v3.w, 7) \
    PAIR(CS.v4.x, CS.v4.y, 8) PAIR(CS.v4.z, CS.v4.w, 9) \
    float rd = racc[0] + racc[1]; \
    if(padw) Xs[(TT_)*XS_STRIDE + d] = act ? f2bf(rd) : (unsigned short)0; }
  #define SLOT(K, EAr, CSr, QAr, QVr) { \
    STEP(tt+(K), EAr, CSr) \
    LD_EAF(EAr, QAr) \
    LD_CORRF(CSr, QVr) \
    { int g8 = c*CLEN + tt + (K) + 8; int ix = (g8 < S_) ? g8 : S_-1; \
      QAr = qap[ix]; QVr = qp[ix]; } }

  #pragma unroll 1
  for(int c=0;c<CHK;++c){
    // roll qpre one chunk ahead (consumed by NEXT iteration's hq gather)
    int qpreN[4];
    { int cn = (c+1 < CHK) ? c+1 : c;
      #pragma unroll
      for(int reg=0;reg<4;++reg) qpreN[reg] = qp[cn*CLEN + mbase + quad*4 + reg]; }

    // ---- 32-step scan, period-4 modulo schedule ----
    #pragma unroll 1
    for(int tt=0; tt<CLEN; tt+=4){
      SLOT(0, ea0, cs0, qa_i0, qv_i0)
      SLOT(1, ea1, cs1, qa_i1, qv_i1)
      SLOT(2, ea2, cs2, qa_i2, qv_i2)
      SLOT(3, ea3, cs3, qa_i3, qv_i3)
    }

    // hq gather for this chunk (qpreC loaded a full chunk ago; used post-MFMA)
    float hqv[4][2];
    #pragma unroll
    for(int reg=0;reg<4;++reg)
      #pragma unroll
      for(int j=0;j<2;++j)
        hqv[reg][j] = hq[qpreC[reg]*64 + (nh*2+j)*16 + col];

    __syncthreads();

    f32x4_t acc[2];
    acc[0] = (f32x4_t){0.f,0.f,0.f,0.f};
    acc[1] = (f32x4_t){0.f,0.f,0.f,0.f};
    #pragma unroll
    for(int ks=0;ks<NKS;++ks){
      bf16x8_t a = *reinterpret_cast<const bf16x8_t*>(Xs + (mbase+col)*XS_STRIDE + quad*8 + ks*32);
      #pragma unroll
      for(int j=0;j<2;++j){
        int nt = nh*2 + j;
        bf16x8_t bfr = *reinterpret_cast<const bf16x8_t*>(WpFrag + ((size_t)(ks*4+nt)*64 + lane)*8);
        acc[j] = __builtin_amdgcn_mfma_f32_16x16x32_bf16(a, bfr, acc[j], 0, 0, 0);
      }
    }

    float part[4];
    #pragma unroll
    for(int reg=0;reg<4;++reg){
      float s = 0.f;
      #pragma unroll
      for(int j=0;j<2;++j){
        float h = acc[j][reg] + hqv[reg][j];
        s = fmaf(pwv[j], ftanh(h), s);
      }
      part[reg] = s;
    }
    #pragma unroll
    for(int off=1; off<16; off<<=1){
      #pragma unroll
      for(int reg=0;reg<4;++reg) part[reg] += __shfl_xor(part[reg], off, 64);
    }
    if(col == 0){
      #pragma unroll
      for(int reg=0;reg<4;++reg) sred[rt][nh][quad*4+reg] = part[reg];
    }
    __syncthreads();

    if(nh == 0 && col == 0){
      #pragma unroll
      for(int reg=0;reg<4;++reg){
        int idx = quad*4 + reg;
        int mloc = mbase + idx;
        int row = b*S_ + c*CLEN + mloc;
        float logit = sred[rt][0][idx] + sred[rt][1][idx] + pbv;
        out[1+row] = fsigm(logit);
        float t = target[row];
        if(t >= 0.f){
          cntAcc += 1.f;
          bceAcc += fmaxf(logit,0.f) - logit*t + log1pf(__expf(-fabsf(logit)));
        }
      }
    }
    #pragma unroll
    for(int reg=0;reg<4;++reg) qpreC[reg] = qpreN[reg];
  }
  #undef SLOT
  #undef STEP
  #undef PAIR
  #undef LD_CORRF
  #undef LD_EAF

  bceAcc += __shfl_xor(bceAcc, 16, 64); cntAcc += __shfl_xor(cntAcc, 16, 64);
  bceAcc += __shfl_xor(bceAcc, 32, 64); cntAcc += __shfl_xor(cntAcc, 32, 64);
  if(lane == 0 && nh == 0){ sbce[wave] = bceAcc; sbce[2+wave] = cntAcc; }
  __syncthreads();
  if(threadIdx.x == 0)
    partials[b] = make_float2(sbce[0]+sbce[1], sbce[2]+sbce[3]);
}

// K2: reduce per-block partials -> loss (256 partials)
__global__ __launch_bounds__(256) void k_fin(const float2* __restrict__ partials,
                                             float* __restrict__ out){
  float2 p = partials[threadIdx.x];
  float bce = p.x, cnt = p.y;
  #pragma unroll
  for(int off=32; off>0; off>>=1){
    bce += __shfl_down(bce, off, 64);
    cnt += __shfl_down(cnt, off, 64);
  }
  __shared__ float sb[4], sc[4];
  int w = threadIdx.x >> 6;
  if((threadIdx.x & 63) == 0){ sb[w] = bce; sc[w] = cnt; }
  __syncthreads();
  if(threadIdx.x == 0){
    float Bt = sb[0]+sb[1]+sb[2]+sb[3];
    float Ct = sc[0]+sc[1]+sc[2]+sc[3];
    out[0] = Bt / fmaxf(Ct, 1.f);
  }
}

extern "C" void kernel_launch(void* const* d_in, const int* in_sizes, int n_in,
                              void* d_out, int out_size, void* d_ws, size_t ws_size,
                              hipStream_t stream){
  const int*   qd     = (const int*)d_in[0];
  const int*   qad    = (const int*)d_in[1];
  const float* target = (const float*)d_in[2];
  const float* qw     = (const float*)d_in[3];
  const float* qaw    = (const float*)d_in[4];
  const float* mk     = (const float*)d_in[5];
  const float* mv0    = (const float*)d_in[6];
  const float* ew     = (const float*)d_in[7];
  const float* eb     = (const float*)d_in[8];
  const float* aw     = (const float*)d_in[9];
  const float* ab     = (const float*)d_in[10];
  const float* rw     = (const float*)d_in[11];
  const float* rb     = (const float*)d_in[12];
  const float* pw     = (const float*)d_in[13];
  const float* pb     = (const float*)d_in[14];
  float* out = (float*)d_out;

  char* ws = (char*)d_ws;
  size_t off = 0;
  float2* partials = (float2*)(ws + off);            off += (((size_t)B_*8 + 255)/256)*256;
  float* corrF    = (float*)(ws + off);              off += (((size_t)(NQ_+1)*CORRF_STRIDE*4 + 255)/256)*256;
  float2* eaTabF  = (float2*)(ws + off);             off += (((size_t)(2*NQ_+1)*DV_*8 + 255)/256)*256;
  unsigned short* WpFrag = (unsigned short*)(ws + off); off += ((size_t)NKS*4*64*8*2 + 255)/256*256;
  float* pwPad    = (float*)(ws + off);              off += 256;
  float* hq       = (float*)(ws + off);              off += (size_t)(NQ_+1)*64*4;

  k_prep1<<<dim3(PREP_BLOCKS), dim3(256), 0, stream>>>(qaw, ew, eb, aw, ab, eaTabF,
                                                       qw, mk, corrF,
                                                       rw, rb, pw, WpFrag, pwPad, hq);
  k_seq<<<dim3(B_), dim3(256), 0, stream>>>(qd, qad, corrF, eaTabF, mv0,
                                            WpFrag, hq, pwPad, pb, target, out, partials);
  k_fin<<<dim3(1), dim3(256), 0, stream>>>(partials, out);
}